// Round 1
// baseline (341.297 us; speedup 1.0000x reference)
//
#include <hip/hip_runtime.h>
#include <stdint.h>

// Problem constants
#define LSEQ 2048
#define EMB  1024
#define NH   16
#define HWID 64
#define SCALEF 0.125f   // 1/sqrt(64)

typedef __attribute__((ext_vector_type(4))) float  f32x4;
typedef __attribute__((ext_vector_type(8))) short  bf16x8;   // 8 bf16 in 4 VGPRs (MFMA operand)
typedef __attribute__((ext_vector_type(8))) unsigned short u16x8;
typedef __attribute__((ext_vector_type(4))) unsigned short u16x4;

static __device__ __forceinline__ unsigned short f2bf(float f) {
    union { float f; unsigned int u; } v; v.f = f;
    unsigned int r = (v.u + 0x7FFFu + ((v.u >> 16) & 1u)) >> 16;  // RNE
    return (unsigned short)r;
}
static __device__ __forceinline__ float bf2f(unsigned short h) {
    union { unsigned int u; float f; } v; v.u = ((unsigned int)h) << 16;
    return v.f;
}

static __device__ __forceinline__ void gload_lds16(const void* g, void* l) {
    __builtin_amdgcn_global_load_lds((const __attribute__((address_space(1))) void*)g,
                                     (__attribute__((address_space(3))) void*)l,
                                     16, 0, 0);
}

// ---------------------------------------------------------------------------
// K0: fp32 -> bf16 conversion of x, [w_proj;w_g] (concat as 4096x1024), w_o
// ---------------------------------------------------------------------------
__global__ __launch_bounds__(256) void convert_kernel(
    const float* __restrict__ x, const float* __restrict__ wp,
    const float* __restrict__ wg, const float* __restrict__ wo,
    unsigned short* __restrict__ xb, unsigned short* __restrict__ wcat,
    unsigned short* __restrict__ wob)
{
    const int NX  = (LSEQ * EMB) / 4;        // 524288 float4
    const int NWP = (3 * EMB * EMB) / 4;     // 786432
    const int NWG = (EMB * EMB) / 4;         // 262144
    const int NWO = (EMB * EMB) / 4;
    const int total = NX + NWP + NWG + NWO;
    for (int i = blockIdx.x * blockDim.x + threadIdx.x; i < total;
         i += gridDim.x * blockDim.x) {
        const float4* src; unsigned short* dst; int j;
        if (i < NX)                  { src = (const float4*)x;  dst = xb;                  j = i; }
        else if (i < NX + NWP)       { src = (const float4*)wp; dst = wcat;                j = i - NX; }
        else if (i < NX + NWP + NWG) { src = (const float4*)wg; dst = wcat + 3 * EMB * EMB; j = i - NX - NWP; }
        else                         { src = (const float4*)wo; dst = wob;                 j = i - NX - NWP - NWG; }
        float4 v = src[j];
        u16x4 o;
        o.x = f2bf(v.x); o.y = f2bf(v.y); o.z = f2bf(v.z); o.w = f2bf(v.w);
        *(u16x4*)(dst + (size_t)j * 4) = o;
    }
}

// ---------------------------------------------------------------------------
// Mask decode: tolerate bool(1B) / int32 / float32 encodings.
// bool(p=0.9): ~90% nonzero bytes. int32: ~22%. f32: ~45%. Threshold 50%.
// ---------------------------------------------------------------------------
__global__ void decode_mask_kernel(const unsigned char* __restrict__ mask,
                                   unsigned char* __restrict__ valid)
{
    __shared__ int cnt;
    if (threadIdx.x == 0) cnt = 0;
    __syncthreads();
    int c = 0;
    for (int i = threadIdx.x; i < LSEQ; i += 256) c += (mask[i] != 0);
    atomicAdd(&cnt, c);
    __syncthreads();
    bool isbyte = cnt > LSEQ / 2;
    for (int k = threadIdx.x; k < LSEQ; k += 256) {
        unsigned char v;
        if (isbyte) v = (mask[k] != 0);
        else        v = ((mask[4*k] | mask[4*k+1] | mask[4*k+2] | mask[4*k+3]) != 0);
        valid[k] = v;
    }
}

// ---------------------------------------------------------------------------
// GEMM: C[M,N] = A[M,K] * B[N,K]^T   (A,B bf16 row-major; B in B^T form)
// m97-style: 128x128 tile, BK=64, 4 waves (2x2), 4x4 16x16x32 frags/wave,
// global_load_lds width-16 staging.
// epi==0: write bf16 C. epi==1: write f32 C + biasN[col].
// ---------------------------------------------------------------------------
#define BM 128
#define BN 128
#define BK 64

__global__ __launch_bounds__(256) void gemm_bt_kernel(
    const unsigned short* __restrict__ A, const unsigned short* __restrict__ B,
    void* __restrict__ Cout, const float* __restrict__ biasN,
    int M, int N, int K, int epi)
{
    __shared__ unsigned short As[BM][BK];   // 16 KB
    __shared__ unsigned short Bs[BN][BK];   // 16 KB
    const int tid  = threadIdx.x;
    const int lane = tid & 63;
    const int w    = tid >> 6;
    const int wr   = w >> 1, wc = w & 1;
    const int row0 = blockIdx.y * BM;
    const int col0 = blockIdx.x * BN;
    const int lr = lane & 15;
    const int lg = lane >> 4;

    f32x4 acc[4][4];
    const f32x4 zf = {0.f, 0.f, 0.f, 0.f};
#pragma unroll
    for (int m = 0; m < 4; ++m)
#pragma unroll
        for (int n = 0; n < 4; ++n) acc[m][n] = zf;

    const char* Ab = (const char*)(A + (size_t)row0 * K);
    const char* Bb = (const char*)(B + (size_t)col0 * K);
    const int Kb = K * 2;

    for (int kt = 0; kt < K; kt += BK) {
#pragma unroll
        for (int i = 0; i < 4; ++i) {
            int o = (i * 256 + tid) * 16;
            int r = o >> 7, cb = o & 127;
            gload_lds16(Ab + (size_t)r * Kb + kt * 2 + cb, (char*)As + o);
        }
#pragma unroll
        for (int i = 0; i < 4; ++i) {
            int o = (i * 256 + tid) * 16;
            int r = o >> 7, cb = o & 127;
            gload_lds16(Bb + (size_t)r * Kb + kt * 2 + cb, (char*)Bs + o);
        }
        __syncthreads();
#pragma unroll
        for (int kk = 0; kk < 2; ++kk) {
            bf16x8 af[4], bfr[4];
            const int lk = kk * 32 + lg * 8;
#pragma unroll
            for (int m = 0; m < 4; ++m) af[m]  = *(const bf16x8*)&As[wr * 64 + m * 16 + lr][lk];
#pragma unroll
            for (int n = 0; n < 4; ++n) bfr[n] = *(const bf16x8*)&Bs[wc * 64 + n * 16 + lr][lk];
#pragma unroll
            for (int m = 0; m < 4; ++m)
#pragma unroll
                for (int n = 0; n < 4; ++n)
                    acc[m][n] = __builtin_amdgcn_mfma_f32_16x16x32_bf16(af[m], bfr[n], acc[m][n], 0, 0, 0);
        }
        __syncthreads();
    }

#pragma unroll
    for (int m = 0; m < 4; ++m)
#pragma unroll
        for (int n = 0; n < 4; ++n) {
            const int col = col0 + wc * 64 + n * 16 + lr;
#pragma unroll
            for (int r = 0; r < 4; ++r) {
                const int row = row0 + wr * 64 + m * 16 + lg * 4 + r;
                if (epi == 0)
                    ((unsigned short*)Cout)[(size_t)row * N + col] = f2bf(acc[m][n][r]);
                else
                    ((float*)Cout)[(size_t)row * N + col] = acc[m][n][r] + biasN[col];
            }
        }
}

// ---------------------------------------------------------------------------
// K2a: rearrange proj output T[L,4096]: Q/K -> [h][l][64]; gate -> sigmoid
// ---------------------------------------------------------------------------
__global__ __launch_bounds__(256) void rearrange_kernel(
    const unsigned short* __restrict__ T, const float* __restrict__ bg,
    unsigned short* __restrict__ Qh, unsigned short* __restrict__ Kh,
    unsigned short* __restrict__ G)
{
    const int l = blockIdx.x;
    const int t = threadIdx.x;
    const unsigned short* trow = T + (size_t)l * 4096;
    {
        const int tt = t & 127;
        const int h  = tt >> 3;
        const int c0 = (tt & 7) * 8;
        const int srcoff = h * 192 + ((t < 128) ? 0 : 64) + c0;
        u16x8 v = *(const u16x8*)(trow + srcoff);
        unsigned short* dst = ((t < 128) ? Qh : Kh) + ((size_t)h * LSEQ + l) * HWID + c0;
        *(u16x8*)dst = v;
    }
    {
        const int f0 = t * 4;
        float4 b4 = *(const float4*)(bg + f0);
        u16x4 tv = *(const u16x4*)(trow + 3 * EMB + f0);
        u16x4 o;
        o.x = f2bf(1.f / (1.f + __expf(-(bf2f(tv.x) + b4.x))));
        o.y = f2bf(1.f / (1.f + __expf(-(bf2f(tv.y) + b4.y))));
        o.z = f2bf(1.f / (1.f + __expf(-(bf2f(tv.z) + b4.z))));
        o.w = f2bf(1.f / (1.f + __expf(-(bf2f(tv.w) + b4.w))));
        *(u16x4*)(G + (size_t)l * EMB + f0) = o;
    }
}

// ---------------------------------------------------------------------------
// K2b: V transpose -> VT[h][c][l] via 64x64 LDS tiles
// ---------------------------------------------------------------------------
__global__ __launch_bounds__(256) void vtrans_kernel(
    const unsigned short* __restrict__ T, unsigned short* __restrict__ VT)
{
    __shared__ unsigned short tile[64][72];  // pad 8 shorts
    const int h  = blockIdx.x & 15;
    const int lt = blockIdx.x >> 4;          // 0..31
    const int l0 = lt * 64;
    const int t  = threadIdx.x;
    {
        const int i = t >> 2, c0 = (t & 3) * 16;
        const unsigned short* src = T + (size_t)(l0 + i) * 4096 + h * 192 + 128;
        *(u16x8*)&tile[i][c0]     = *(const u16x8*)(src + c0);
        *(u16x8*)&tile[i][c0 + 8] = *(const u16x8*)(src + c0 + 8);
    }
    __syncthreads();
    {
        const int c = t >> 2, j0 = (t & 3) * 16;
        unsigned short* dst = VT + ((size_t)h * HWID + c) * LSEQ + l0 + j0;
        u16x8 a, b;
#pragma unroll
        for (int j = 0; j < 8; ++j) a[j] = tile[j0 + j][c];
#pragma unroll
        for (int j = 0; j < 8; ++j) b[j] = tile[j0 + 8 + j][c];
        *(u16x8*)dst       = a;
        *(u16x8*)(dst + 8) = b;
    }
}

// ---------------------------------------------------------------------------
// K3: fused attention. Block = 512 thr (8 waves) = 4 heads x 2 q-subtiles of 16.
// Block covers q-tile of 32 rows, head group of 4 -> bias loads are float4
// (4 heads/lane) fully coalesced, staged in LDS, exactly-once HBM traffic.
// Per wave: flash over k in steps of 32; QK^T/PV via 16x16x32 bf16 MFMA;
// K/V fragments read directly from global (L2/L3-resident).
// ---------------------------------------------------------------------------
__global__ __launch_bounds__(512) void attn_kernel(
    const unsigned short* __restrict__ Qh, const unsigned short* __restrict__ Kh,
    const unsigned short* __restrict__ VT, const unsigned short* __restrict__ G,
    const float* __restrict__ bias, const unsigned char* __restrict__ valid,
    unsigned short* __restrict__ Y)
{
    __shared__ float bias_s[4][32][33];          // [h-local][q-local][k] (pad)
    __shared__ unsigned short ps[8][16][40];     // per-wave P buffer (pad->80B rows)

    const int tid  = threadIdx.x;
    const int lane = tid & 63;
    const int w    = tid >> 6;
    const int qt   = blockIdx.x >> 2;
    const int hg   = blockIdx.x & 3;
    const int h    = hg * 4 + (w & 3);
    const int q0b  = qt * 32;
    const int q0w  = q0b + (w >> 2) * 16;
    const int lr   = lane & 15;
    const int lg   = lane >> 4;

    const unsigned short* Qbase = Qh + ((size_t)h * LSEQ + q0w) * HWID;
    const bf16x8 qa0 = *(const bf16x8*)(Qbase + lr * HWID + lg * 8);
    const bf16x8 qa1 = *(const bf16x8*)(Qbase + lr * HWID + 32 + lg * 8);

    const unsigned short* Kbase = Kh + (size_t)h * LSEQ * HWID;
    const unsigned short* Vbase = VT + (size_t)h * HWID * LSEQ;

    float mrow[4], lrow[4];
    f32x4 acc[4];
    const f32x4 zf = {0.f, 0.f, 0.f, 0.f};
#pragma unroll
    for (int r = 0; r < 4; ++r) { mrow[r] = -1e30f; lrow[r] = 0.f; }
#pragma unroll
    for (int c = 0; c < 4; ++c) acc[c] = zf;

    const int hloc  = w & 3;
    const int qbias = (w >> 2) * 16 + lg * 4;

    for (int kt = 0; kt < LSEQ; kt += 32) {
        __syncthreads();
        // cooperative bias stage: 32q x 32k x 4h  (float4 = 4 heads per lane)
#pragma unroll
        for (int it = 0; it < 2; ++it) {
            const int p = tid + it * 512;
            const int q = p >> 5, k = p & 31;
            const float4 bv = *(const float4*)(bias +
                ((size_t)(q0b + q) * LSEQ + (kt + k)) * NH + hg * 4);
            bias_s[0][q][k] = bv.x; bias_s[1][q][k] = bv.y;
            bias_s[2][q][k] = bv.z; bias_s[3][q][k] = bv.w;
        }
        __syncthreads();

        // S = Q K^T  (two 16-key column tiles)
        f32x4 S[2];
#pragma unroll
        for (int t2 = 0; t2 < 2; ++t2) {
            const unsigned short* kp = Kbase + (size_t)(kt + t2 * 16 + lr) * HWID + lg * 8;
            bf16x8 kb0 = *(const bf16x8*)kp;
            bf16x8 kb1 = *(const bf16x8*)(kp + 32);
            f32x4 s = zf;
            s = __builtin_amdgcn_mfma_f32_16x16x32_bf16(qa0, kb0, s, 0, 0, 0);
            s = __builtin_amdgcn_mfma_f32_16x16x32_bf16(qa1, kb1, s, 0, 0, 0);
            S[t2] = s;
        }

        const bool v0 = valid[kt + lr] != 0;
        const bool v1 = valid[kt + 16 + lr] != 0;

        float sc[2][4], rm[4];
#pragma unroll
        for (int r = 0; r < 4; ++r) {
            float s0 = S[0][r] * SCALEF + bias_s[hloc][qbias + r][lr];
            float s1 = S[1][r] * SCALEF + bias_s[hloc][qbias + r][16 + lr];
            sc[0][r] = v0 ? s0 : -1e30f;
            sc[1][r] = v1 ? s1 : -1e30f;
            rm[r] = fmaxf(sc[0][r], sc[1][r]);
        }
#pragma unroll
        for (int off = 1; off < 16; off <<= 1)
#pragma unroll
            for (int r = 0; r < 4; ++r)
                rm[r] = fmaxf(rm[r], __shfl_xor(rm[r], off, 64));

        float sf[4], rs[4], p0[4], p1[4];
#pragma unroll
        for (int r = 0; r < 4; ++r) {
            const float mn = fmaxf(mrow[r], rm[r]);
            sf[r] = __expf(mrow[r] - mn);
            mrow[r] = mn;
            p0[r] = v0 ? __expf(sc[0][r] - mn) : 0.f;
            p1[r] = v1 ? __expf(sc[1][r] - mn) : 0.f;
            rs[r] = p0[r] + p1[r];
        }
#pragma unroll
        for (int off = 1; off < 16; off <<= 1)
#pragma unroll
            for (int r = 0; r < 4; ++r)
                rs[r] += __shfl_xor(rs[r], off, 64);
#pragma unroll
        for (int r = 0; r < 4; ++r) lrow[r] = lrow[r] * sf[r] + rs[r];

        // rescale accumulators (row r lives at acc[ct][r] for this lane)
#pragma unroll
        for (int ct = 0; ct < 4; ++ct)
#pragma unroll
            for (int r = 0; r < 4; ++r) acc[ct][r] *= sf[r];

        // P -> per-wave LDS (S-layout write, A-frag-layout read)
#pragma unroll
        for (int r = 0; r < 4; ++r) {
            ps[w][lg * 4 + r][lr]      = f2bf(p0[r]);
            ps[w][lg * 4 + r][16 + lr] = f2bf(p1[r]);
        }
        const bf16x8 pa = *(const bf16x8*)&ps[w][lr][lg * 8];

        // PV: y[q][c] += P[q][k] * V[k][c]   (B-frag from VT, direct global)
#pragma unroll
        for (int ct = 0; ct < 4; ++ct) {
            bf16x8 vb = *(const bf16x8*)(Vbase + (size_t)(ct * 16 + lr) * LSEQ + kt + lg * 8);
            acc[ct] = __builtin_amdgcn_mfma_f32_16x16x32_bf16(pa, vb, acc[ct], 0, 0, 0);
        }
    }

    // epilogue: normalize, apply gate, write bf16 Y[q][h*64+c]
    float inv[4];
#pragma unroll
    for (int r = 0; r < 4; ++r) inv[r] = 1.f / lrow[r];
#pragma unroll
    for (int ct = 0; ct < 4; ++ct)
#pragma unroll
        for (int r = 0; r < 4; ++r) {
            const int q = q0w + lg * 4 + r;
            const int e = h * HWID + ct * 16 + lr;
            const float yv = acc[ct][r] * inv[r] * bf2f(G[(size_t)q * EMB + e]);
            Y[(size_t)q * EMB + e] = f2bf(yv);
        }
}

// ---------------------------------------------------------------------------
extern "C" void kernel_launch(void* const* d_in, const int* in_sizes, int n_in,
                              void* d_out, int out_size, void* d_ws, size_t ws_size,
                              hipStream_t stream) {
    const float*         x      = (const float*)d_in[0];
    const unsigned char* mask   = (const unsigned char*)d_in[1];
    const float*         bias   = (const float*)d_in[2];
    const float*         w_proj = (const float*)d_in[3];
    const float*         w_o    = (const float*)d_in[4];
    const float*         b_o    = (const float*)d_in[5];
    const float*         w_g    = (const float*)d_in[6];
    const float*         b_g    = (const float*)d_in[7];
    float* out = (float*)d_out;
    (void)in_sizes; (void)n_in; (void)out_size; (void)ws_size;

    char* p = (char*)d_ws;
    auto alloc = [&](size_t bytes) {
        char* r = p; p += (bytes + 255) & ~(size_t)255; return r;
    };
    unsigned short* xb    = (unsigned short*)alloc((size_t)LSEQ * EMB * 2);
    unsigned short* wcat  = (unsigned short*)alloc((size_t)4 * EMB * EMB * 2);
    unsigned short* wob   = (unsigned short*)alloc((size_t)EMB * EMB * 2);
    unsigned short* T     = (unsigned short*)alloc((size_t)LSEQ * 4096 * 2);
    unsigned short* Qh    = (unsigned short*)alloc((size_t)NH * LSEQ * HWID * 2);
    unsigned short* Kh    = (unsigned short*)alloc((size_t)NH * LSEQ * HWID * 2);
    unsigned short* VT    = (unsigned short*)alloc((size_t)NH * HWID * LSEQ * 2);
    unsigned short* G     = (unsigned short*)alloc((size_t)LSEQ * EMB * 2);
    unsigned short* Yb    = (unsigned short*)alloc((size_t)LSEQ * EMB * 2);
    unsigned char*  vmask = (unsigned char*)alloc(LSEQ);

    convert_kernel<<<1024, 256, 0, stream>>>(x, w_proj, w_g, w_o, xb, wcat, wob);
    decode_mask_kernel<<<1, 256, 0, stream>>>(mask, vmask);
    gemm_bt_kernel<<<dim3(4096 / BN, LSEQ / BM), 256, 0, stream>>>(
        xb, wcat, (void*)T, nullptr, LSEQ, 4096, EMB, 0);
    rearrange_kernel<<<LSEQ, 256, 0, stream>>>(T, b_g, Qh, Kh, G);
    vtrans_kernel<<<NH * (LSEQ / 64), 256, 0, stream>>>(T, VT);
    attn_kernel<<<(LSEQ / 32) * 4, 512, 0, stream>>>(Qh, Kh, VT, G, bias, vmask, Yb);
    gemm_bt_kernel<<<dim3(EMB / BN, LSEQ / BM), 256, 0, stream>>>(
        Yb, wob, (void*)out, b_o, LSEQ, EMB, EMB, 1);
}

// Round 2
// 298.116 us; speedup vs baseline: 1.1448x; 1.1448x over previous
//
#include <hip/hip_runtime.h>
#include <stdint.h>

// Problem constants
#define LSEQ 2048
#define EMB  1024
#define NH   16
#define HWID 64
#define SCALEF 0.125f   // 1/sqrt(64)

typedef __attribute__((ext_vector_type(4))) float  f32x4;
typedef __attribute__((ext_vector_type(8))) short  bf16x8;   // 8 bf16 in 4 VGPRs (MFMA operand)
typedef __attribute__((ext_vector_type(8))) unsigned short u16x8;
typedef __attribute__((ext_vector_type(4))) unsigned short u16x4;

static __device__ __forceinline__ unsigned short f2bf(float f) {
    union { float f; unsigned int u; } v; v.f = f;
    unsigned int r = (v.u + 0x7FFFu + ((v.u >> 16) & 1u)) >> 16;  // RNE
    return (unsigned short)r;
}
static __device__ __forceinline__ float bf2f(unsigned short h) {
    union { unsigned int u; float f; } v; v.u = ((unsigned int)h) << 16;
    return v.f;
}

static __device__ __forceinline__ void gload_lds16(const void* g, void* l) {
    __builtin_amdgcn_global_load_lds((const __attribute__((address_space(1))) void*)g,
                                     (__attribute__((address_space(3))) void*)l,
                                     16, 0, 0);
}

// ---------------------------------------------------------------------------
// K0: fp32 -> bf16 conversion of x, [w_proj;w_g] (concat as 4096x1024), w_o
// ---------------------------------------------------------------------------
__global__ __launch_bounds__(256) void convert_kernel(
    const float* __restrict__ x, const float* __restrict__ wp,
    const float* __restrict__ wg, const float* __restrict__ wo,
    unsigned short* __restrict__ xb, unsigned short* __restrict__ wcat,
    unsigned short* __restrict__ wob)
{
    const int NX  = (LSEQ * EMB) / 4;        // 524288 float4
    const int NWP = (3 * EMB * EMB) / 4;     // 786432
    const int NWG = (EMB * EMB) / 4;         // 262144
    const int NWO = (EMB * EMB) / 4;
    const int total = NX + NWP + NWG + NWO;
    for (int i = blockIdx.x * blockDim.x + threadIdx.x; i < total;
         i += gridDim.x * blockDim.x) {
        const float4* src; unsigned short* dst; int j;
        if (i < NX)                  { src = (const float4*)x;  dst = xb;                  j = i; }
        else if (i < NX + NWP)       { src = (const float4*)wp; dst = wcat;                j = i - NX; }
        else if (i < NX + NWP + NWG) { src = (const float4*)wg; dst = wcat + 3 * EMB * EMB; j = i - NX - NWP; }
        else                         { src = (const float4*)wo; dst = wob;                 j = i - NX - NWP - NWG; }
        float4 v = src[j];
        u16x4 o;
        o.x = f2bf(v.x); o.y = f2bf(v.y); o.z = f2bf(v.z); o.w = f2bf(v.w);
        *(u16x4*)(dst + (size_t)j * 4) = o;
    }
}

// ---------------------------------------------------------------------------
// Mask decode: tolerate bool(1B) / int32 / float32 encodings.
// ---------------------------------------------------------------------------
__global__ void decode_mask_kernel(const unsigned char* __restrict__ mask,
                                   unsigned char* __restrict__ valid)
{
    __shared__ int cnt;
    if (threadIdx.x == 0) cnt = 0;
    __syncthreads();
    int c = 0;
    for (int i = threadIdx.x; i < LSEQ; i += 256) c += (mask[i] != 0);
    atomicAdd(&cnt, c);
    __syncthreads();
    bool isbyte = cnt > LSEQ / 2;
    for (int k = threadIdx.x; k < LSEQ; k += 256) {
        unsigned char v;
        if (isbyte) v = (mask[k] != 0);
        else        v = ((mask[4*k] | mask[4*k+1] | mask[4*k+2] | mask[4*k+3]) != 0);
        valid[k] = v;
    }
}

// ---------------------------------------------------------------------------
// GEMM: C[M,N] = A[M,K] * B[N,K]^T  (m97-style 128x128, BK=64)
// ---------------------------------------------------------------------------
#define BM 128
#define BN 128
#define BK 64

__global__ __launch_bounds__(256) void gemm_bt_kernel(
    const unsigned short* __restrict__ A, const unsigned short* __restrict__ B,
    void* __restrict__ Cout, const float* __restrict__ biasN,
    int M, int N, int K, int epi)
{
    __shared__ unsigned short As[BM][BK];   // 16 KB
    __shared__ unsigned short Bs[BN][BK];   // 16 KB
    const int tid  = threadIdx.x;
    const int lane = tid & 63;
    const int w    = tid >> 6;
    const int wr   = w >> 1, wc = w & 1;
    const int row0 = blockIdx.y * BM;
    const int col0 = blockIdx.x * BN;
    const int lr = lane & 15;
    const int lg = lane >> 4;

    f32x4 acc[4][4];
    const f32x4 zf = {0.f, 0.f, 0.f, 0.f};
#pragma unroll
    for (int m = 0; m < 4; ++m)
#pragma unroll
        for (int n = 0; n < 4; ++n) acc[m][n] = zf;

    const char* Ab = (const char*)(A + (size_t)row0 * K);
    const char* Bb = (const char*)(B + (size_t)col0 * K);
    const int Kb = K * 2;

    for (int kt = 0; kt < K; kt += BK) {
#pragma unroll
        for (int i = 0; i < 4; ++i) {
            int o = (i * 256 + tid) * 16;
            int r = o >> 7, cb = o & 127;
            gload_lds16(Ab + (size_t)r * Kb + kt * 2 + cb, (char*)As + o);
        }
#pragma unroll
        for (int i = 0; i < 4; ++i) {
            int o = (i * 256 + tid) * 16;
            int r = o >> 7, cb = o & 127;
            gload_lds16(Bb + (size_t)r * Kb + kt * 2 + cb, (char*)Bs + o);
        }
        __syncthreads();
#pragma unroll
        for (int kk = 0; kk < 2; ++kk) {
            bf16x8 af[4], bfr[4];
            const int lk = kk * 32 + lg * 8;
#pragma unroll
            for (int m = 0; m < 4; ++m) af[m]  = *(const bf16x8*)&As[wr * 64 + m * 16 + lr][lk];
#pragma unroll
            for (int n = 0; n < 4; ++n) bfr[n] = *(const bf16x8*)&Bs[wc * 64 + n * 16 + lr][lk];
#pragma unroll
            for (int m = 0; m < 4; ++m)
#pragma unroll
                for (int n = 0; n < 4; ++n)
                    acc[m][n] = __builtin_amdgcn_mfma_f32_16x16x32_bf16(af[m], bfr[n], acc[m][n], 0, 0, 0);
        }
        __syncthreads();
    }

#pragma unroll
    for (int m = 0; m < 4; ++m)
#pragma unroll
        for (int n = 0; n < 4; ++n) {
            const int col = col0 + wc * 64 + n * 16 + lr;
#pragma unroll
            for (int r = 0; r < 4; ++r) {
                const int row = row0 + wr * 64 + m * 16 + lg * 4 + r;
                if (epi == 0)
                    ((unsigned short*)Cout)[(size_t)row * N + col] = f2bf(acc[m][n][r]);
                else
                    ((float*)Cout)[(size_t)row * N + col] = acc[m][n][r] + biasN[col];
            }
        }
}

// ---------------------------------------------------------------------------
// K2a: rearrange proj output T[L,4096]: Q/K -> [h][l][64]; gate -> sigmoid
// ---------------------------------------------------------------------------
__global__ __launch_bounds__(256) void rearrange_kernel(
    const unsigned short* __restrict__ T, const float* __restrict__ bg,
    unsigned short* __restrict__ Qh, unsigned short* __restrict__ Kh,
    unsigned short* __restrict__ G)
{
    const int l = blockIdx.x;
    const int t = threadIdx.x;
    const unsigned short* trow = T + (size_t)l * 4096;
    {
        const int tt = t & 127;
        const int h  = tt >> 3;
        const int c0 = (tt & 7) * 8;
        const int srcoff = h * 192 + ((t < 128) ? 0 : 64) + c0;
        u16x8 v = *(const u16x8*)(trow + srcoff);
        unsigned short* dst = ((t < 128) ? Qh : Kh) + ((size_t)h * LSEQ + l) * HWID + c0;
        *(u16x8*)dst = v;
    }
    {
        const int f0 = t * 4;
        float4 b4 = *(const float4*)(bg + f0);
        u16x4 tv = *(const u16x4*)(trow + 3 * EMB + f0);
        u16x4 o;
        o.x = f2bf(1.f / (1.f + __expf(-(bf2f(tv.x) + b4.x))));
        o.y = f2bf(1.f / (1.f + __expf(-(bf2f(tv.y) + b4.y))));
        o.z = f2bf(1.f / (1.f + __expf(-(bf2f(tv.z) + b4.z))));
        o.w = f2bf(1.f / (1.f + __expf(-(bf2f(tv.w) + b4.w))));
        *(u16x4*)(G + (size_t)l * EMB + f0) = o;
    }
}

// ---------------------------------------------------------------------------
// K2b: V transpose -> VT[h][c][l] via 64x64 LDS tiles
// ---------------------------------------------------------------------------
__global__ __launch_bounds__(256) void vtrans_kernel(
    const unsigned short* __restrict__ T, unsigned short* __restrict__ VT)
{
    __shared__ unsigned short tile[64][72];
    const int h  = blockIdx.x & 15;
    const int lt = blockIdx.x >> 4;
    const int l0 = lt * 64;
    const int t  = threadIdx.x;
    {
        const int i = t >> 2, c0 = (t & 3) * 16;
        const unsigned short* src = T + (size_t)(l0 + i) * 4096 + h * 192 + 128;
        *(u16x8*)&tile[i][c0]     = *(const u16x8*)(src + c0);
        *(u16x8*)&tile[i][c0 + 8] = *(const u16x8*)(src + c0 + 8);
    }
    __syncthreads();
    {
        const int c = t >> 2, j0 = (t & 3) * 16;
        unsigned short* dst = VT + ((size_t)h * HWID + c) * LSEQ + l0 + j0;
        u16x8 a, b;
#pragma unroll
        for (int j = 0; j < 8; ++j) a[j] = tile[j0 + j][c];
#pragma unroll
        for (int j = 0; j < 8; ++j) b[j] = tile[j0 + 8 + j][c];
        *(u16x8*)dst       = a;
        *(u16x8*)(dst + 8) = b;
    }
}

// ---------------------------------------------------------------------------
// K3: fused attention, software-pipelined bias stream.
// Block = 512 thr (8 waves) = 4 heads x 2 q-subtiles of 16; q-tile 32, KT=64.
// Registers carry bias tile t+1 (4 x float4/thread) while tile t computes.
// Per iter: LDS-write staged tile -> barrier -> QK^T/softmax/PV -> barrier.
// XCD-grouping swizzle: 4 head-group blocks of a q-tile land on one XCD so
// each 64B bias line is fetched from HBM once.
// ---------------------------------------------------------------------------
__global__ __launch_bounds__(512) void attn_kernel(
    const unsigned short* __restrict__ Qh, const unsigned short* __restrict__ Kh,
    const unsigned short* __restrict__ VT, const unsigned short* __restrict__ G,
    const float* __restrict__ bias, const unsigned char* __restrict__ valid,
    unsigned short* __restrict__ Y)
{
    __shared__ float bias_s[4][32][68];          // 34 KB, stride 68: 2-way reads
    __shared__ unsigned short ps[8][16][72];     // 18.4 KB per-wave P buffers
    __shared__ unsigned char vld[LSEQ];          // 2 KB mask cache

    const int tid  = threadIdx.x;
    const int lane = tid & 63;
    const int w    = tid >> 6;
    // XCD-grouping swizzle: members {c + 8j + 32r} share qt=r*8+c, hg=j
    const int bi   = blockIdx.x;
    const int qt   = (bi >> 5) * 8 + (bi & 7);
    const int hg   = (bi >> 3) & 3;
    const int h    = hg * 4 + (w & 3);
    const int q0b  = qt * 32;
    const int q0w  = q0b + (w >> 2) * 16;
    const int lr   = lane & 15;
    const int lg   = lane >> 4;
    const int hloc = w & 3;
    const int qbias = (w >> 2) * 16 + lg * 4;

    // stage mask once
    {
        const unsigned char* mp = valid + tid * 4;
        uchar4 m4 = *(const uchar4*)mp;
        *(uchar4*)(vld + tid * 4) = m4;
    }

    const unsigned short* Qbase = Qh + ((size_t)h * LSEQ + q0w) * HWID;
    const bf16x8 qa0 = *(const bf16x8*)(Qbase + lr * HWID + lg * 8);
    const bf16x8 qa1 = *(const bf16x8*)(Qbase + lr * HWID + 32 + lg * 8);

    const unsigned short* Kbase = Kh + (size_t)h * LSEQ * HWID;
    const unsigned short* Vbase = VT + (size_t)h * HWID * LSEQ;

    // bias staging: thread -> (q=tid>>4, k=bu+16i), float4 = 4 heads of hg
    const int bq = tid >> 4;
    const int bu = tid & 15;
    const float* bsrc = bias + (size_t)(q0b + bq) * LSEQ * NH + hg * 4;

    float mrow[4], lrow[4];
    f32x4 acc[4];
    const f32x4 zf = {0.f, 0.f, 0.f, 0.f};
#pragma unroll
    for (int r = 0; r < 4; ++r) { mrow[r] = -1e30f; lrow[r] = 0.f; }
#pragma unroll
    for (int c = 0; c < 4; ++c) acc[c] = zf;

    // prologue: load bias tile 0
    float4 br[4];
#pragma unroll
    for (int i = 0; i < 4; ++i)
        br[i] = *(const float4*)(bsrc + (size_t)(bu + 16 * i) * NH);

    for (int t = 0; t < 32; ++t) {
        const int k0 = t * 64;
        // 1. write staged tile t to LDS (data already in regs)
#pragma unroll
        for (int i = 0; i < 4; ++i) {
            const int k = bu + 16 * i;
            bias_s[0][bq][k] = br[i].x;
            bias_s[1][bq][k] = br[i].y;
            bias_s[2][bq][k] = br[i].z;
            bias_s[3][bq][k] = br[i].w;
        }
        // 2. issue prefetch of tile t+1 (completes during compute below)
        const int kn = (t < 31) ? (k0 + 64) : 0;
        float4 brn[4];
#pragma unroll
        for (int i = 0; i < 4; ++i)
            brn[i] = *(const float4*)(bsrc + (size_t)(kn + bu + 16 * i) * NH);
        __syncthreads();

        // 3. QK^T over 64 keys (4 column tiles of 16)
        f32x4 S[4];
#pragma unroll
        for (int t2 = 0; t2 < 4; ++t2) {
            const unsigned short* kp = Kbase + (size_t)(k0 + t2 * 16 + lr) * HWID + lg * 8;
            bf16x8 kb0 = *(const bf16x8*)kp;
            bf16x8 kb1 = *(const bf16x8*)(kp + 32);
            f32x4 s = zf;
            s = __builtin_amdgcn_mfma_f32_16x16x32_bf16(qa0, kb0, s, 0, 0, 0);
            s = __builtin_amdgcn_mfma_f32_16x16x32_bf16(qa1, kb1, s, 0, 0, 0);
            S[t2] = s;
        }

        bool v[4];
#pragma unroll
        for (int t2 = 0; t2 < 4; ++t2) v[t2] = vld[k0 + lr + 16 * t2] != 0;

        // 4. scores + online softmax
        float sc[4][4], rm[4];
#pragma unroll
        for (int r = 0; r < 4; ++r) {
            rm[r] = -1e30f;
#pragma unroll
            for (int t2 = 0; t2 < 4; ++t2) {
                float s = S[t2][r] * SCALEF + bias_s[hloc][qbias + r][lr + 16 * t2];
                sc[t2][r] = v[t2] ? s : -1e30f;
                rm[r] = fmaxf(rm[r], sc[t2][r]);
            }
        }
#pragma unroll
        for (int off = 1; off < 16; off <<= 1)
#pragma unroll
            for (int r = 0; r < 4; ++r)
                rm[r] = fmaxf(rm[r], __shfl_xor(rm[r], off, 64));

        float sf[4], rs[4], p[4][4];
#pragma unroll
        for (int r = 0; r < 4; ++r) {
            const float mn = fmaxf(mrow[r], rm[r]);
            sf[r] = __expf(mrow[r] - mn);
            mrow[r] = mn;
            rs[r] = 0.f;
#pragma unroll
            for (int t2 = 0; t2 < 4; ++t2) {
                p[t2][r] = v[t2] ? __expf(sc[t2][r] - mn) : 0.f;
                rs[r] += p[t2][r];
            }
        }
#pragma unroll
        for (int off = 1; off < 16; off <<= 1)
#pragma unroll
            for (int r = 0; r < 4; ++r)
                rs[r] += __shfl_xor(rs[r], off, 64);
#pragma unroll
        for (int r = 0; r < 4; ++r) lrow[r] = lrow[r] * sf[r] + rs[r];

#pragma unroll
        for (int ct = 0; ct < 4; ++ct)
#pragma unroll
            for (int r = 0; r < 4; ++r) acc[ct][r] *= sf[r];

        // 5. P -> per-wave LDS (transpose to A-frag layout); wave-local
#pragma unroll
        for (int r = 0; r < 4; ++r)
#pragma unroll
            for (int t2 = 0; t2 < 4; ++t2)
                ps[w][lg * 4 + r][lr + 16 * t2] = f2bf(p[t2][r]);
        const bf16x8 pa0 = *(const bf16x8*)&ps[w][lr][lg * 8];
        const bf16x8 pa1 = *(const bf16x8*)&ps[w][lr][32 + lg * 8];

        // 6. PV over the 64-key chunk
#pragma unroll
        for (int ct = 0; ct < 4; ++ct) {
            const unsigned short* vp = Vbase + (size_t)(ct * 16 + lr) * LSEQ + k0 + lg * 8;
            bf16x8 vb0 = *(const bf16x8*)vp;
            bf16x8 vb1 = *(const bf16x8*)(vp + 32);
            acc[ct] = __builtin_amdgcn_mfma_f32_16x16x32_bf16(pa0, vb0, acc[ct], 0, 0, 0);
            acc[ct] = __builtin_amdgcn_mfma_f32_16x16x32_bf16(pa1, vb1, acc[ct], 0, 0, 0);
        }
        __syncthreads();
#pragma unroll
        for (int i = 0; i < 4; ++i) br[i] = brn[i];
    }

    // epilogue: normalize, gate, write bf16 Y
    float inv[4];
#pragma unroll
    for (int r = 0; r < 4; ++r) inv[r] = 1.f / lrow[r];
#pragma unroll
    for (int ct = 0; ct < 4; ++ct)
#pragma unroll
        for (int r = 0; r < 4; ++r) {
            const int q = q0w + lg * 4 + r;
            const int e = h * HWID + ct * 16 + lr;
            const float yv = acc[ct][r] * inv[r] * bf2f(G[(size_t)q * EMB + e]);
            Y[(size_t)q * EMB + e] = f2bf(yv);
        }
}

// ---------------------------------------------------------------------------
extern "C" void kernel_launch(void* const* d_in, const int* in_sizes, int n_in,
                              void* d_out, int out_size, void* d_ws, size_t ws_size,
                              hipStream_t stream) {
    const float*         x      = (const float*)d_in[0];
    const unsigned char* mask   = (const unsigned char*)d_in[1];
    const float*         bias   = (const float*)d_in[2];
    const float*         w_proj = (const float*)d_in[3];
    const float*         w_o    = (const float*)d_in[4];
    const float*         b_o    = (const float*)d_in[5];
    const float*         w_g    = (const float*)d_in[6];
    const float*         b_g    = (const float*)d_in[7];
    float* out = (float*)d_out;
    (void)in_sizes; (void)n_in; (void)out_size; (void)ws_size;

    char* p = (char*)d_ws;
    auto alloc = [&](size_t bytes) {
        char* r = p; p += (bytes + 255) & ~(size_t)255; return r;
    };
    unsigned short* xb    = (unsigned short*)alloc((size_t)LSEQ * EMB * 2);
    unsigned short* wcat  = (unsigned short*)alloc((size_t)4 * EMB * EMB * 2);
    unsigned short* wob   = (unsigned short*)alloc((size_t)EMB * EMB * 2);
    unsigned short* T     = (unsigned short*)alloc((size_t)LSEQ * 4096 * 2);
    unsigned short* Qh    = (unsigned short*)alloc((size_t)NH * LSEQ * HWID * 2);
    unsigned short* Kh    = (unsigned short*)alloc((size_t)NH * LSEQ * HWID * 2);
    unsigned short* VT    = (unsigned short*)alloc((size_t)NH * HWID * LSEQ * 2);
    unsigned short* G     = (unsigned short*)alloc((size_t)LSEQ * EMB * 2);
    unsigned short* Yb    = (unsigned short*)alloc((size_t)LSEQ * EMB * 2);
    unsigned char*  vmask = (unsigned char*)alloc(LSEQ);

    convert_kernel<<<1024, 256, 0, stream>>>(x, w_proj, w_g, w_o, xb, wcat, wob);
    decode_mask_kernel<<<1, 256, 0, stream>>>(mask, vmask);
    gemm_bt_kernel<<<dim3(4096 / BN, LSEQ / BM), 256, 0, stream>>>(
        xb, wcat, (void*)T, nullptr, LSEQ, 4096, EMB, 0);
    rearrange_kernel<<<LSEQ, 256, 0, stream>>>(T, b_g, Qh, Kh, G);
    vtrans_kernel<<<NH * (LSEQ / 64), 256, 0, stream>>>(T, VT);
    attn_kernel<<<(LSEQ / 32) * 4, 512, 0, stream>>>(Qh, Kh, VT, G, bias, vmask, Yb);
    gemm_bt_kernel<<<dim3(EMB / BN, LSEQ / BM), 256, 0, stream>>>(
        Yb, wob, (void*)out, b_o, LSEQ, EMB, EMB, 1);
}

// Round 3
// 267.935 us; speedup vs baseline: 1.2738x; 1.1126x over previous
//
#include <hip/hip_runtime.h>
#include <stdint.h>

// Problem constants
#define LSEQ 2048
#define EMB  1024
#define NH   16
#define HWID 64
#define SCALEF 0.125f   // 1/sqrt(64)

typedef __attribute__((ext_vector_type(4))) float  f32x4;
typedef __attribute__((ext_vector_type(8))) short  bf16x8;   // 8 bf16 in 4 VGPRs (MFMA operand)
typedef __attribute__((ext_vector_type(8))) unsigned short u16x8;
typedef __attribute__((ext_vector_type(4))) unsigned short u16x4;

static __device__ __forceinline__ unsigned short f2bf(float f) {
    union { float f; unsigned int u; } v; v.f = f;
    unsigned int r = (v.u + 0x7FFFu + ((v.u >> 16) & 1u)) >> 16;  // RNE
    return (unsigned short)r;
}
static __device__ __forceinline__ float bf2f(unsigned short h) {
    union { unsigned int u; float f; } v; v.u = ((unsigned int)h) << 16;
    return v.f;
}

static __device__ __forceinline__ void gload_lds16(const void* g, void* l) {
    __builtin_amdgcn_global_load_lds((const __attribute__((address_space(1))) void*)g,
                                     (__attribute__((address_space(3))) void*)l,
                                     16, 0, 0);
}

// ---------------------------------------------------------------------------
// K0: fp32 -> bf16 conversion of x, [w_proj;w_g] (concat as 4096x1024), w_o
// ---------------------------------------------------------------------------
__global__ __launch_bounds__(256) void convert_kernel(
    const float* __restrict__ x, const float* __restrict__ wp,
    const float* __restrict__ wg, const float* __restrict__ wo,
    unsigned short* __restrict__ xb, unsigned short* __restrict__ wcat,
    unsigned short* __restrict__ wob)
{
    const int NX  = (LSEQ * EMB) / 4;
    const int NWP = (3 * EMB * EMB) / 4;
    const int NWG = (EMB * EMB) / 4;
    const int NWO = (EMB * EMB) / 4;
    const int total = NX + NWP + NWG + NWO;
    for (int i = blockIdx.x * blockDim.x + threadIdx.x; i < total;
         i += gridDim.x * blockDim.x) {
        const float4* src; unsigned short* dst; int j;
        if (i < NX)                  { src = (const float4*)x;  dst = xb;                  j = i; }
        else if (i < NX + NWP)       { src = (const float4*)wp; dst = wcat;                j = i - NX; }
        else if (i < NX + NWP + NWG) { src = (const float4*)wg; dst = wcat + 3 * EMB * EMB; j = i - NX - NWP; }
        else                         { src = (const float4*)wo; dst = wob;                 j = i - NX - NWP - NWG; }
        float4 v = src[j];
        u16x4 o;
        o.x = f2bf(v.x); o.y = f2bf(v.y); o.z = f2bf(v.z); o.w = f2bf(v.w);
        *(u16x4*)(dst + (size_t)j * 4) = o;
    }
}

// ---------------------------------------------------------------------------
// Mask decode: tolerate bool(1B) / int32 / float32 encodings.
// ---------------------------------------------------------------------------
__global__ void decode_mask_kernel(const unsigned char* __restrict__ mask,
                                   unsigned char* __restrict__ valid)
{
    __shared__ int cnt;
    if (threadIdx.x == 0) cnt = 0;
    __syncthreads();
    int c = 0;
    for (int i = threadIdx.x; i < LSEQ; i += 256) c += (mask[i] != 0);
    atomicAdd(&cnt, c);
    __syncthreads();
    bool isbyte = cnt > LSEQ / 2;
    for (int k = threadIdx.x; k < LSEQ; k += 256) {
        unsigned char v;
        if (isbyte) v = (mask[k] != 0);
        else        v = ((mask[4*k] | mask[4*k+1] | mask[4*k+2] | mask[4*k+3]) != 0);
        valid[k] = v;
    }
}

// ---------------------------------------------------------------------------
// GEMM: C[M,N] = A[M,K] * B[N,K]^T  (m97-style 128x128, BK=64)
// ---------------------------------------------------------------------------
#define BM 128
#define BN 128
#define BK 64

__global__ __launch_bounds__(256) void gemm_bt_kernel(
    const unsigned short* __restrict__ A, const unsigned short* __restrict__ B,
    void* __restrict__ Cout, const float* __restrict__ biasN,
    int M, int N, int K, int epi)
{
    __shared__ unsigned short As[BM][BK];
    __shared__ unsigned short Bs[BN][BK];
    const int tid  = threadIdx.x;
    const int lane = tid & 63;
    const int w    = tid >> 6;
    const int wr   = w >> 1, wc = w & 1;
    const int row0 = blockIdx.y * BM;
    const int col0 = blockIdx.x * BN;
    const int lr = lane & 15;
    const int lg = lane >> 4;

    f32x4 acc[4][4];
    const f32x4 zf = {0.f, 0.f, 0.f, 0.f};
#pragma unroll
    for (int m = 0; m < 4; ++m)
#pragma unroll
        for (int n = 0; n < 4; ++n) acc[m][n] = zf;

    const char* Ab = (const char*)(A + (size_t)row0 * K);
    const char* Bb = (const char*)(B + (size_t)col0 * K);
    const int Kb = K * 2;

    for (int kt = 0; kt < K; kt += BK) {
#pragma unroll
        for (int i = 0; i < 4; ++i) {
            int o = (i * 256 + tid) * 16;
            int r = o >> 7, cb = o & 127;
            gload_lds16(Ab + (size_t)r * Kb + kt * 2 + cb, (char*)As + o);
        }
#pragma unroll
        for (int i = 0; i < 4; ++i) {
            int o = (i * 256 + tid) * 16;
            int r = o >> 7, cb = o & 127;
            gload_lds16(Bb + (size_t)r * Kb + kt * 2 + cb, (char*)Bs + o);
        }
        __syncthreads();
#pragma unroll
        for (int kk = 0; kk < 2; ++kk) {
            bf16x8 af[4], bfr[4];
            const int lk = kk * 32 + lg * 8;
#pragma unroll
            for (int m = 0; m < 4; ++m) af[m]  = *(const bf16x8*)&As[wr * 64 + m * 16 + lr][lk];
#pragma unroll
            for (int n = 0; n < 4; ++n) bfr[n] = *(const bf16x8*)&Bs[wc * 64 + n * 16 + lr][lk];
#pragma unroll
            for (int m = 0; m < 4; ++m)
#pragma unroll
                for (int n = 0; n < 4; ++n)
                    acc[m][n] = __builtin_amdgcn_mfma_f32_16x16x32_bf16(af[m], bfr[n], acc[m][n], 0, 0, 0);
        }
        __syncthreads();
    }

#pragma unroll
    for (int m = 0; m < 4; ++m)
#pragma unroll
        for (int n = 0; n < 4; ++n) {
            const int col = col0 + wc * 64 + n * 16 + lr;
#pragma unroll
            for (int r = 0; r < 4; ++r) {
                const int row = row0 + wr * 64 + m * 16 + lg * 4 + r;
                if (epi == 0)
                    ((unsigned short*)Cout)[(size_t)row * N + col] = f2bf(acc[m][n][r]);
                else
                    ((float*)Cout)[(size_t)row * N + col] = acc[m][n][r] + biasN[col];
            }
        }
}

// ---------------------------------------------------------------------------
// K2a: rearrange proj output T[L,4096]: Q/K -> [h][l][64]; gate -> sigmoid
// ---------------------------------------------------------------------------
__global__ __launch_bounds__(256) void rearrange_kernel(
    const unsigned short* __restrict__ T, const float* __restrict__ bg,
    unsigned short* __restrict__ Qh, unsigned short* __restrict__ Kh,
    unsigned short* __restrict__ G)
{
    const int l = blockIdx.x;
    const int t = threadIdx.x;
    const unsigned short* trow = T + (size_t)l * 4096;
    {
        const int tt = t & 127;
        const int h  = tt >> 3;
        const int c0 = (tt & 7) * 8;
        const int srcoff = h * 192 + ((t < 128) ? 0 : 64) + c0;
        u16x8 v = *(const u16x8*)(trow + srcoff);
        unsigned short* dst = ((t < 128) ? Qh : Kh) + ((size_t)h * LSEQ + l) * HWID + c0;
        *(u16x8*)dst = v;
    }
    {
        const int f0 = t * 4;
        float4 b4 = *(const float4*)(bg + f0);
        u16x4 tv = *(const u16x4*)(trow + 3 * EMB + f0);
        u16x4 o;
        o.x = f2bf(1.f / (1.f + __expf(-(bf2f(tv.x) + b4.x))));
        o.y = f2bf(1.f / (1.f + __expf(-(bf2f(tv.y) + b4.y))));
        o.z = f2bf(1.f / (1.f + __expf(-(bf2f(tv.z) + b4.z))));
        o.w = f2bf(1.f / (1.f + __expf(-(bf2f(tv.w) + b4.w))));
        *(u16x4*)(G + (size_t)l * EMB + f0) = o;
    }
}

// ---------------------------------------------------------------------------
// K2b: V transpose -> VT[h][c][l] via 64x64 LDS tiles
// ---------------------------------------------------------------------------
__global__ __launch_bounds__(256) void vtrans_kernel(
    const unsigned short* __restrict__ T, unsigned short* __restrict__ VT)
{
    __shared__ unsigned short tile[64][72];
    const int h  = blockIdx.x & 15;
    const int lt = blockIdx.x >> 4;
    const int l0 = lt * 64;
    const int t  = threadIdx.x;
    {
        const int i = t >> 2, c0 = (t & 3) * 16;
        const unsigned short* src = T + (size_t)(l0 + i) * 4096 + h * 192 + 128;
        *(u16x8*)&tile[i][c0]     = *(const u16x8*)(src + c0);
        *(u16x8*)&tile[i][c0 + 8] = *(const u16x8*)(src + c0 + 8);
    }
    __syncthreads();
    {
        const int c = t >> 2, j0 = (t & 3) * 16;
        unsigned short* dst = VT + ((size_t)h * HWID + c) * LSEQ + l0 + j0;
        u16x8 a, b;
#pragma unroll
        for (int j = 0; j < 8; ++j) a[j] = tile[j0 + j][c];
#pragma unroll
        for (int j = 0; j < 8; ++j) b[j] = tile[j0 + 8 + j][c];
        *(u16x8*)dst       = a;
        *(u16x8*)(dst + 8) = b;
    }
}

// ---------------------------------------------------------------------------
// K3: fused attention, counted-vmcnt ring pipeline + split-k(2).
// Grid 512 = 64 qt x 4 hg x 2 splits; block 512 thr = 8 waves
// (4 heads x 2 q-subtiles); 2 blocks/CU -> 16 waves/CU of TLP.
// Bias staged global->LDS ring (3 slots) via global_load_lds; loop uses raw
// s_barrier + asm vmcnt(2) so stage ops stay in flight across barriers.
// Partial (unnormalized O, m, l) per split written to ws; combine_kernel
// merges + applies gate.
// ---------------------------------------------------------------------------
#define KT   32
#define RING 3
#define NT   32                       // tiles per split: 1024 / KT
#define SLOT_BYTES (KT * 32 * 16)     // 32q x 32k float4 = 16 KB

__global__ __launch_bounds__(512, 4) void attn_kernel(
    const unsigned short* __restrict__ Qh, const unsigned short* __restrict__ Kh,
    const unsigned short* __restrict__ VT, const float* __restrict__ bias,
    const unsigned char* __restrict__ valid,
    float* __restrict__ Op, float* __restrict__ Ml)
{
    __shared__ char ring[RING * SLOT_BYTES];     // 48 KB
    __shared__ unsigned short ps[8][16][40];     // 10 KB per-wave P buffers

    const int tid  = threadIdx.x;
    const int lane = tid & 63;
    const int w    = tid >> 6;
    // swizzle: bi = r*32 + j*8 + c ; XCD (bi%8)=c shared by the 4 hg blocks
    const int bi = blockIdx.x;
    const int cxl = bi & 7;
    const int hg  = (bi >> 3) & 3;
    const int rr  = bi >> 5;
    const int u   = rr * 8 + cxl;     // [0,128)
    const int qt  = u >> 1;           // [0,64)
    const int sp  = u & 1;            // split
    const int h    = hg * 4 + (w & 3);
    const int q0b  = qt * 32;
    const int q0w  = q0b + (w >> 2) * 16;
    const int koff = sp * 1024;
    const int lr   = lane & 15;
    const int lg   = lane >> 4;
    const int hloc = w & 3;
    const int qloc = (w >> 2) * 16 + lg * 4;   // block-local base q of this lane's rows

    const unsigned short* Qbase = Qh + ((size_t)h * LSEQ + q0w) * HWID;
    const bf16x8 qa0 = *(const bf16x8*)(Qbase + lr * HWID + lg * 8);
    const bf16x8 qa1 = *(const bf16x8*)(Qbase + lr * HWID + 32 + lg * 8);

    const unsigned short* Kbase = Kh + (size_t)h * LSEQ * HWID;
    const unsigned short* Vbase = VT + (size_t)h * HWID * LSEQ;
    const char* bias_base = (const char*)bias;

    // stage one 32q x 32k float4 tile into ring slot (wave-linear LDS dest)
    auto stage = [&](int t) {
        char* dst = ring + (t % RING) * SLOT_BYTES;
        const int kg = koff + t * KT;
#pragma unroll
        for (int p = 0; p < 2; ++p) {
            const int i = p * 512 + tid;
            const int q = i >> 5, k = i & 31;
            gload_lds16(bias_base + ((size_t)(q0b + q) * LSEQ + (kg + k)) * 64 + hg * 16,
                        dst + i * 16);
        }
    };

    float mrow[4], lrow[4];
    f32x4 acc[4];
    const f32x4 zf = {0.f, 0.f, 0.f, 0.f};
#pragma unroll
    for (int r = 0; r < 4; ++r) { mrow[r] = -1e30f; lrow[r] = 0.f; }
#pragma unroll
    for (int c = 0; c < 4; ++c) acc[c] = zf;

    stage(0);
    stage(1);

    for (int t = 0; t < NT; ++t) {
        asm volatile("s_waitcnt vmcnt(2)" ::: "memory");
        __builtin_amdgcn_s_barrier();
        asm volatile("" ::: "memory");

        const int kg = koff + t * KT;
        const float* bs = (const float*)(ring + (t % RING) * SLOT_BYTES);

        const bool v0 = valid[kg + lr] != 0;
        const bool v1 = valid[kg + 16 + lr] != 0;

        // QK^T over 32 keys (2 column tiles of 16)
        f32x4 S[2];
#pragma unroll
        for (int t2 = 0; t2 < 2; ++t2) {
            const unsigned short* kp = Kbase + (size_t)(kg + t2 * 16 + lr) * HWID + lg * 8;
            bf16x8 kb0 = *(const bf16x8*)kp;
            bf16x8 kb1 = *(const bf16x8*)(kp + 32);
            f32x4 s = zf;
            s = __builtin_amdgcn_mfma_f32_16x16x32_bf16(qa0, kb0, s, 0, 0, 0);
            s = __builtin_amdgcn_mfma_f32_16x16x32_bf16(qa1, kb1, s, 0, 0, 0);
            S[t2] = s;
        }

        // scores: S*scale + bias (extract head component hloc from float4 tile)
        float sc[2][4], rm[4];
#pragma unroll
        for (int r = 0; r < 4; ++r) {
            const float b0 = bs[(((qloc + r) * 32) + lr) * 4 + hloc];
            const float b1 = bs[(((qloc + r) * 32) + 16 + lr) * 4 + hloc];
            sc[0][r] = v0 ? (S[0][r] * SCALEF + b0) : -1e30f;
            sc[1][r] = v1 ? (S[1][r] * SCALEF + b1) : -1e30f;
            rm[r] = fmaxf(sc[0][r], sc[1][r]);
        }
#pragma unroll
        for (int off = 1; off < 16; off <<= 1)
#pragma unroll
            for (int r = 0; r < 4; ++r)
                rm[r] = fmaxf(rm[r], __shfl_xor(rm[r], off, 64));

        float sf[4], rs[4], p0[4], p1[4];
#pragma unroll
        for (int r = 0; r < 4; ++r) {
            const float mn = fmaxf(mrow[r], rm[r]);
            sf[r] = __expf(mrow[r] - mn);
            mrow[r] = mn;
            p0[r] = v0 ? __expf(sc[0][r] - mn) : 0.f;
            p1[r] = v1 ? __expf(sc[1][r] - mn) : 0.f;
            rs[r] = p0[r] + p1[r];
        }
#pragma unroll
        for (int off = 1; off < 16; off <<= 1)
#pragma unroll
            for (int r = 0; r < 4; ++r)
                rs[r] += __shfl_xor(rs[r], off, 64);
#pragma unroll
        for (int r = 0; r < 4; ++r) lrow[r] = lrow[r] * sf[r] + rs[r];

#pragma unroll
        for (int ct = 0; ct < 4; ++ct)
#pragma unroll
            for (int r = 0; r < 4; ++r) acc[ct][r] *= sf[r];

        // P -> per-wave LDS (transpose to A-frag layout); wave-local
#pragma unroll
        for (int r = 0; r < 4; ++r) {
            ps[w][lg * 4 + r][lr]      = f2bf(p0[r]);
            ps[w][lg * 4 + r][16 + lr] = f2bf(p1[r]);
        }
        const bf16x8 pa = *(const bf16x8*)&ps[w][lr][lg * 8];

        // PV over the 32-key chunk
#pragma unroll
        for (int ct = 0; ct < 4; ++ct) {
            bf16x8 vb = *(const bf16x8*)(Vbase + (size_t)(ct * 16 + lr) * LSEQ + kg + lg * 8);
            acc[ct] = __builtin_amdgcn_mfma_f32_16x16x32_bf16(pa, vb, acc[ct], 0, 0, 0);
        }

        if (t + 2 < NT) stage(t + 2);
    }

    // store partials (unnormalized)
    const size_t rowb = ((size_t)sp * NH + h) * LSEQ;
#pragma unroll
    for (int ct = 0; ct < 4; ++ct)
#pragma unroll
        for (int r = 0; r < 4; ++r) {
            const int q = q0w + lg * 4 + r;
            Op[(rowb + q) * HWID + ct * 16 + lr] = acc[ct][r];
        }
    if (lr == 0) {
#pragma unroll
        for (int r = 0; r < 4; ++r) {
            const int q = q0w + lg * 4 + r;
            Ml[(rowb + q) * 2 + 0] = mrow[r];
            Ml[(rowb + q) * 2 + 1] = lrow[r];
        }
    }
}

// ---------------------------------------------------------------------------
// K3b: combine split-k partials, normalize, apply gate -> bf16 Y
// ---------------------------------------------------------------------------
__global__ __launch_bounds__(256) void combine_kernel(
    const float* __restrict__ Op, const float* __restrict__ Ml,
    const unsigned short* __restrict__ G, unsigned short* __restrict__ Yb)
{
    const int t   = threadIdx.x;
    const int c   = t & 63;
    const int row = blockIdx.x * 4 + (t >> 6);      // [0, NH*LSEQ)
    const int h   = row >> 11;
    const int q   = row & (LSEQ - 1);
    const size_t r0 = (size_t)h * LSEQ + q;
    const size_t r1 = ((size_t)NH + h) * LSEQ + q;
    const float m0 = Ml[r0 * 2 + 0], l0 = Ml[r0 * 2 + 1];
    const float m1 = Ml[r1 * 2 + 0], l1 = Ml[r1 * 2 + 1];
    const float mx = fmaxf(m0, m1);
    const float a0 = __expf(m0 - mx), a1 = __expf(m1 - mx);
    const float inv = 1.f / (l0 * a0 + l1 * a1);
    const float o0 = Op[r0 * HWID + c];
    const float o1 = Op[r1 * HWID + c];
    const float y = (o0 * a0 + o1 * a1) * inv;
    const int e = h * HWID + c;
    const float g = bf2f(G[(size_t)q * EMB + e]);
    Yb[(size_t)q * EMB + e] = f2bf(y * g);
}

// ---------------------------------------------------------------------------
extern "C" void kernel_launch(void* const* d_in, const int* in_sizes, int n_in,
                              void* d_out, int out_size, void* d_ws, size_t ws_size,
                              hipStream_t stream) {
    const float*         x      = (const float*)d_in[0];
    const unsigned char* mask   = (const unsigned char*)d_in[1];
    const float*         bias   = (const float*)d_in[2];
    const float*         w_proj = (const float*)d_in[3];
    const float*         w_o    = (const float*)d_in[4];
    const float*         b_o    = (const float*)d_in[5];
    const float*         w_g    = (const float*)d_in[6];
    const float*         b_g    = (const float*)d_in[7];
    float* out = (float*)d_out;
    (void)in_sizes; (void)n_in; (void)out_size; (void)ws_size;

    char* p = (char*)d_ws;
    auto alloc = [&](size_t bytes) {
        char* r = p; p += (bytes + 255) & ~(size_t)255; return r;
    };
    unsigned short* xb    = (unsigned short*)alloc((size_t)LSEQ * EMB * 2);
    unsigned short* wcat  = (unsigned short*)alloc((size_t)4 * EMB * EMB * 2);
    unsigned short* wob   = (unsigned short*)alloc((size_t)EMB * EMB * 2);
    unsigned short* T     = (unsigned short*)alloc((size_t)LSEQ * 4096 * 2);
    unsigned short* Qh    = (unsigned short*)alloc((size_t)NH * LSEQ * HWID * 2);
    unsigned short* Kh    = (unsigned short*)alloc((size_t)NH * LSEQ * HWID * 2);
    unsigned short* VT    = (unsigned short*)alloc((size_t)NH * HWID * LSEQ * 2);
    unsigned short* G     = (unsigned short*)alloc((size_t)LSEQ * EMB * 2);
    unsigned short* Yb    = (unsigned short*)alloc((size_t)LSEQ * EMB * 2);
    unsigned char*  vmask = (unsigned char*)alloc(LSEQ);
    float*          Op    = (float*)alloc((size_t)2 * NH * LSEQ * HWID * 4);
    float*          Ml    = (float*)alloc((size_t)2 * NH * LSEQ * 2 * 4);

    convert_kernel<<<1024, 256, 0, stream>>>(x, w_proj, w_g, w_o, xb, wcat, wob);
    decode_mask_kernel<<<1, 256, 0, stream>>>(mask, vmask);
    gemm_bt_kernel<<<dim3(4096 / BN, LSEQ / BM), 256, 0, stream>>>(
        xb, wcat, (void*)T, nullptr, LSEQ, 4096, EMB, 0);
    rearrange_kernel<<<LSEQ, 256, 0, stream>>>(T, b_g, Qh, Kh, G);
    vtrans_kernel<<<NH * (LSEQ / 64), 256, 0, stream>>>(T, VT);
    attn_kernel<<<512, 512, 0, stream>>>(Qh, Kh, VT, bias, vmask, Op, Ml);
    combine_kernel<<<NH * LSEQ / 4, 256, 0, stream>>>(Op, Ml, G, Yb);
    gemm_bt_kernel<<<dim3(EMB / BN, LSEQ / BM), 256, 0, stream>>>(
        Yb, wob, (void*)out, b_o, LSEQ, EMB, EMB, 1);
}